// Round 11
// baseline (1350.391 us; speedup 1.0000x reference)
//
#include <hip/hip_runtime.h>
#include <hip/hip_fp16.h>

#define FDIM 256
#define GRAM_KS 192
#define NB 64

// scaled-fp16 storage: hop h stored = true * 4^-h. Rescales (exact powers of 2):
//   C = G0^T G0: *256 ; Z = G2^T G2: *2^24 ; G2 colsums: *4096 ; G0 colsum: *16

typedef _Float16 f16x8 __attribute__((ext_vector_type(8)));
typedef float f32x4 __attribute__((ext_vector_type(4)));
typedef unsigned int u32x4 __attribute__((ext_vector_type(4)));

union H8 { uint2 u2[2]; f16x8 v; };

// LDS row permutation: kills the 8-way bank conflict of the staging write
// (rows 8t+j at word-col sp: 8*18 words == 16 mod 32 -> 2 banks). perm mixes
// c>>3 into the low bits; both writes and ldfrag b64 reads become conflict-free
// (bank = 18*perm(c) mod 32 distinct over each 16-lane group); alignment kept.
__device__ __forceinline__ int rp7(int c) { return c ^ (c >> 3); }

// load an 8-half MFMA operand fragment from permuted-row LDS tile ldsT[perm(col)][36]
// lane group g = (lane>>4)&3 ; k-slots: {g*4..g*4+3, 16+g*4..16+g*4+3}
// (same k-map used for A and B -> any consistent bijection is valid)
__device__ __forceinline__ f16x8 ldfrag(const __half* ldsT, int m, int g) {
  H8 h;
  const __half* row = ldsT + rp7(m) * 36;
  h.u2[0] = *(const uint2*)(row + g * 4);
  h.u2[1] = *(const uint2*)(row + 16 + g * 4);
  return h.v;
}

__device__ __forceinline__ void h8acc(uint4 u, float* a) {
  float2 t;
  t = __half22float2(*(__half2*)&u.x); a[0] += t.x; a[1] += t.y;
  t = __half22float2(*(__half2*)&u.y); a[2] += t.x; a[3] += t.y;
  t = __half22float2(*(__half2*)&u.z); a[4] += t.x; a[5] += t.y;
  t = __half22float2(*(__half2*)&u.w); a[6] += t.x; a[7] += t.y;
}

// ---------------- CSR build ----------------
__global__ void k_hist(const int* __restrict__ dst, int* __restrict__ deg, int E) {
  int e = blockIdx.x * 256 + threadIdx.x;
  if (e < E) atomicAdd(&deg[dst[e]], 1);
}

__global__ __launch_bounds__(256) void k_blksum(const int* __restrict__ deg,
    int* __restrict__ blksum, int n) {
  int b = blockIdx.x, tid = threadIdx.x;
  int base = b * 1024 + tid * 4;
  int s = 0;
#pragma unroll
  for (int k = 0; k < 4; ++k) if (base + k < n) s += deg[base + k];
  for (int off = 32; off; off >>= 1) s += __shfl_down(s, off);
  __shared__ int ws4[4];
  if ((tid & 63) == 0) ws4[tid >> 6] = s;
  __syncthreads();
  if (tid == 0) blksum[b] = ws4[0] + ws4[1] + ws4[2] + ws4[3];
}

__global__ void k_blkscan(const int* __restrict__ blksum, int* __restrict__ blkoff, int nblk) {
  int lane = threadIdx.x;
  int carry = 0;
  for (int base = 0; base < nblk; base += 64) {
    int v = (base + lane < nblk) ? blksum[base + lane] : 0;
    int x = v;
    for (int off = 1; off < 64; off <<= 1) { int y = __shfl_up(x, off); if (lane >= off) x += y; }
    if (base + lane < nblk) blkoff[base + lane] = carry + x - v;
    carry += __shfl(x, 63);
  }
}

__global__ __launch_bounds__(256) void k_scan_blk(const int* __restrict__ deg,
    const int* __restrict__ blkoff, int* __restrict__ rowptr, int* __restrict__ cursor, int n) {
  int b = blockIdx.x, tid = threadIdx.x;
  int base = b * 1024 + tid * 4;
  int v[4];
#pragma unroll
  for (int k = 0; k < 4; ++k) v[k] = (base + k < n) ? deg[base + k] : 0;
  int s = v[0] + v[1] + v[2] + v[3];
  int lane = tid & 63, w = tid >> 6;
  int x = s;
  for (int off = 1; off < 64; off <<= 1) { int y = __shfl_up(x, off); if (lane >= off) x += y; }
  __shared__ int wsum[4];
  if (lane == 63) wsum[w] = x;
  __syncthreads();
  int wadd = 0;
  for (int i = 0; i < w; ++i) wadd += wsum[i];
  int run = blkoff[b] + wadd + x - s;
#pragma unroll
  for (int k = 0; k < 4; ++k) {
    if (base + k < n) { rowptr[base + k] = run; cursor[base + k] = run; }
    run += v[k];
  }
  if (n >= base && n <= base + 4) rowptr[n] = run;
}

// ---------------- two-phase scatter ----------------
__global__ void k_binit(const int* __restrict__ rowptr, int* __restrict__ gcur,
    int N, int bshift) {
  int b = threadIdx.x;
  if (b < NB) {
    int idx = b << bshift;
    if (idx > N) idx = N;
    gcur[b] = rowptr[idx];
  }
}

// Phase A: partition edges into NB dst-range buckets; per-block LDS staging so
// global writes are long contiguous runs per bucket (no line-sharing amplification)
__global__ __launch_bounds__(256) void k_part(const int* __restrict__ src,
    const int* __restrict__ dst, int* __restrict__ gcur, int2* __restrict__ pairs,
    int E, int bshift) {
  __shared__ int cnt[NB];
  __shared__ int lbase[NB];
  __shared__ int gbase[NB];
  __shared__ int tot;
  __shared__ int2 stg[4096];
  int tid = threadIdx.x;
  int e0 = blockIdx.x * 4096;
  if (tid < NB) cnt[tid] = 0;
  __syncthreads();
  int es[16], ed[16], lp[16];
#pragma unroll
  for (int k = 0; k < 16; ++k) {
    int e = e0 + k * 256 + tid;
    lp[k] = -1;
    if (e < E) {
      es[k] = src[e]; ed[k] = dst[e];
      lp[k] = atomicAdd(&cnt[ed[k] >> bshift], 1);
    }
  }
  __syncthreads();
  if (tid < NB) {
    int v = cnt[tid];
    int x = v;
    for (int off = 1; off < NB; off <<= 1) { int y = __shfl_up(x, off); if (tid >= off) x += y; }
    lbase[tid] = x - v;
    gbase[tid] = atomicAdd(&gcur[tid], v);
    if (tid == NB - 1) tot = x;
  }
  __syncthreads();
#pragma unroll
  for (int k = 0; k < 16; ++k) {
    if (lp[k] >= 0) stg[lbase[ed[k] >> bshift] + lp[k]] = make_int2(es[k], ed[k]);
  }
  __syncthreads();
  int T = tot;
  for (int i = tid; i < T; i += 256) {
    int2 p = stg[i];
    int b = p.y >> bshift;
    pairs[gbase[b] + (i - lbase[b])] = p;
  }
}

// Phase B: one block per bucket; scatter confined to one small region (one XCD's L2)
__global__ __launch_bounds__(512) void k_scat2(const int2* __restrict__ pairs,
    const int* __restrict__ rowptr, int* __restrict__ cursor, int* __restrict__ esrc,
    int N, int bshift) {
  int b = blockIdx.x;
  int i0 = b << bshift, i1 = (b + 1) << bshift;
  if (i0 > N) i0 = N;
  if (i1 > N) i1 = N;
  int lo = rowptr[i0], hi = rowptr[i1];
  for (int i = lo + threadIdx.x; i < hi; i += 512) {
    int2 p = pairs[i];
    int pos = atomicAdd(&cursor[p.y], 1);
    esrc[pos] = p.x;
  }
}

// ---------------- transpose W2,W3 ----------------
__global__ __launch_bounds__(256) void k_tr2(const float* __restrict__ W2,
    const float* __restrict__ W3, float* __restrict__ W2T, float* __restrict__ W3T) {
  __shared__ float tile[64][65];
  const float* src = blockIdx.z ? W3 : W2;
  float* dst = blockIdx.z ? W3T : W2T;
  int i0 = blockIdx.x * 64, j0 = blockIdx.y * 64;
  int tx = threadIdx.x & 63, ty = threadIdx.x >> 6;
#pragma unroll
  for (int m = 0; m < 16; ++m) {
    int r = ty * 16 + m;
    tile[r][tx] = src[(size_t)(i0 + r) * 256 + j0 + tx];
  }
  __syncthreads();
#pragma unroll
  for (int m = 0; m < 16; ++m) {
    int r = ty * 16 + m;
    dst[(size_t)(j0 + r) * 256 + i0 + tx] = tile[tx][r];
  }
}

// ---------------- feature -> fp16 ----------------
__global__ __launch_bounds__(256) void k_f2h(const float* __restrict__ F,
    __half* __restrict__ H, int n4) {
  int i = blockIdx.x * 256 + threadIdx.x;
  if (i >= n4) return;
  float4 v = ((const float4*)F)[i];
  __half2 a = __floats2half2_rn(v.x, v.y);
  __half2 b = __floats2half2_rn(v.z, v.w);
  uint2 u; u.x = *(unsigned int*)&a; u.y = *(unsigned int*)&b;
  ((uint2*)H)[i] = u;
}

// ---------------- fp16 aggregation: persistent waves, one node/wave at a time ----
// 2048 blocks (8/CU) grid-stride over nodes: removes workgroup dispatch-rate
// limits (12500 tiny blocks -> resident waves looping). lane loads uint4; 32
// lanes cover a 256-col row; half-waves take alternating edges; __shfl_xor(32)
// combines. out = sum/4 (nontemporal store keeps gather table in L2).
__global__ __launch_bounds__(256) void k_aggh(const __half* __restrict__ h,
    const int* __restrict__ rowptr, const int* __restrict__ esrc,
    __half* __restrict__ out, int n) {
  int slot = blockIdx.x * 4 + (threadIdx.x >> 6);
  int nslots = gridDim.x * 4;
  int lane = threadIdx.x & 63;
  int half = lane >> 5, l5 = lane & 31;
  const uint4* hv = (const uint4*)h;     // row = 32 x uint4 (8 halves each)
  for (int wid = slot; wid < n; wid += nslots) {
    int beg = rowptr[wid], end = rowptr[wid + 1];
    int m = end - beg;
    float a0[8] = {}, a1[8] = {}, a2[8] = {}, a3[8] = {};
    int g8 = m >> 3;
    int e = beg + half;
    for (int it = 0; it < g8; ++it, e += 8) {
      int s0 = esrc[e], s1 = esrc[e + 2], s2 = esrc[e + 4], s3 = esrc[e + 6];
      uint4 u0 = hv[(size_t)s0 * 32 + l5];
      uint4 u1 = hv[(size_t)s1 * 32 + l5];
      uint4 u2 = hv[(size_t)s2 * 32 + l5];
      uint4 u3 = hv[(size_t)s3 * 32 + l5];
      h8acc(u0, a0); h8acc(u1, a1); h8acc(u2, a2); h8acc(u3, a3);
    }
    for (; e < end; e += 2) {
      uint4 u = hv[(size_t)esrc[e] * 32 + l5];
      h8acc(u, a0);
    }
    float s[8];
#pragma unroll
    for (int j = 0; j < 8; ++j) {
      s[j] = (a0[j] + a1[j]) + (a2[j] + a3[j]);
      s[j] += __shfl_xor(s[j], 32);
      s[j] *= 0.25f;
    }
    if (half == 0) {
      __half2 h0 = __floats2half2_rn(s[0], s[1]);
      __half2 h1 = __floats2half2_rn(s[2], s[3]);
      __half2 h2 = __floats2half2_rn(s[4], s[5]);
      __half2 h3 = __floats2half2_rn(s[6], s[7]);
      u32x4 uo;
      uo.x = *(unsigned int*)&h0; uo.y = *(unsigned int*)&h1;
      uo.z = *(unsigned int*)&h2; uo.w = *(unsigned int*)&h3;
      __builtin_nontemporal_store(uo, (u32x4*)out + (size_t)wid * 32 + l5);
    }
  }
}

// ---------------- dual-graph scalar aggregation (fp32, exact) ----------------
__global__ __launch_bounds__(256) void k_aggv2(const float* __restrict__ in1,
    const float* __restrict__ in2,
    const int* __restrict__ rp1, const int* __restrict__ es1,
    const int* __restrict__ rp2, const int* __restrict__ es2,
    float* __restrict__ out1, float* __restrict__ out2, int n, int useDeg) {
  int t = blockIdx.x * 256 + threadIdx.x;
  int g = t >> 4;
  int sl = t & 15;
  if (g >= 2 * n) return;
  int which = (g >= n) ? 1 : 0;
  int node = which ? g - n : g;
  const int* rp = which ? rp2 : rp1;
  const int* es = which ? es2 : es1;
  const float* in = which ? in2 : in1;
  float* out = which ? out2 : out1;
  int beg = rp[node], end = rp[node + 1];
  float s = 0.f;
  if (useDeg) {
    for (int e = beg + sl; e < end; e += 16) {
      int v = es[e];
      s += (float)(rp[v + 1] - rp[v]);
    }
  } else {
    for (int e = beg + sl; e < end; e += 16) s += in[es[e]];
  }
#pragma unroll
  for (int off = 8; off; off >>= 1) s += __shfl_down(s, off, 16);
  if (sl == 0) out[node] = s;
}

// ---------------- symmetric Gram on fp16 input (MFMA, prefetched staging) -------
// C-tile 128x128 per block, 4 waves in 2x2, each wave 64x64 via 16x16x32 f16 MFMA.
// LDS holds transposed tiles ldsT[perm(col)][k]; next tile's global loads issue
// before the MFMA phase so L3 latency hides under compute.
__global__ __launch_bounds__(256) void k_gram_sym(const __half* __restrict__ Xm,
    float* __restrict__ partial, int N, float* __restrict__ mc) {
  __shared__ __half ldsA[128 * 36];
  __shared__ __half ldsB[128 * 36];
  int tid = threadIdx.x;
  int t = blockIdx.x;                       // 0:(0,0) 1:(0,1) 2:(1,1)
  int i0 = (t == 2) ? 128 : 0;
  int j0 = (t == 0) ? 0 : 128;
  bool diag = (t != 1);
  int z = blockIdx.z;
  int chunk = (N + GRAM_KS - 1) / GRAM_KS;
  int rb = z * chunk, re = min(N, rb + chunk);
  int lane = tid & 63, w = tid >> 6;
  int g = lane >> 4;
  int lm = lane & 15;
  int wm = w >> 1, wn = w & 1;
  int sp = tid >> 4;                         // staging row-pair 0..15
  int sc = (tid & 15) * 8;                   // staging col offset
  int cc = tid & 127, hh = tid >> 7;
  float xP = 0.f;
  f32x4 acc[4][4] = {};
  const __half* Bsrc = diag ? ldsA : ldsB;
  uint4 a0 = {0,0,0,0}, a1 = {0,0,0,0}, b0 = {0,0,0,0}, b1 = {0,0,0,0};
  {
    int r0 = rb + 2 * sp, r1 = r0 + 1;
    if (r0 < re) a0 = *(const uint4*)(Xm + (size_t)r0 * 256 + i0 + sc);
    if (r1 < re) a1 = *(const uint4*)(Xm + (size_t)r1 * 256 + i0 + sc);
    if (!diag) {
      if (r0 < re) b0 = *(const uint4*)(Xm + (size_t)r0 * 256 + j0 + sc);
      if (r1 < re) b1 = *(const uint4*)(Xm + (size_t)r1 * 256 + j0 + sc);
    }
  }
  for (int rr = rb; rr < re; rr += 32) {
    __syncthreads();   // previous-iter LDS reads done
    {
      const unsigned short* pa0 = (const unsigned short*)&a0;
      const unsigned short* pa1 = (const unsigned short*)&a1;
      const unsigned short* pb0 = (const unsigned short*)&b0;
      const unsigned short* pb1 = (const unsigned short*)&b1;
#pragma unroll
      for (int j = 0; j < 8; ++j) {
        *(unsigned int*)(ldsA + rp7(sc + j) * 36 + 2 * sp) =
            (unsigned int)pa0[j] | ((unsigned int)pa1[j] << 16);
        if (!diag)
          *(unsigned int*)(ldsB + rp7(sc + j) * 36 + 2 * sp) =
              (unsigned int)pb0[j] | ((unsigned int)pb1[j] << 16);
      }
    }
    // issue next tile's loads now; they fly under the MFMA phase
    uint4 na0 = {0,0,0,0}, na1 = {0,0,0,0}, nb0 = {0,0,0,0}, nb1 = {0,0,0,0};
    int nr = rr + 32;
    if (nr < re) {
      int r0 = nr + 2 * sp, r1 = r0 + 1;
      if (r0 < re) na0 = *(const uint4*)(Xm + (size_t)r0 * 256 + i0 + sc);
      if (r1 < re) na1 = *(const uint4*)(Xm + (size_t)r1 * 256 + i0 + sc);
      if (!diag) {
        if (r0 < re) nb0 = *(const uint4*)(Xm + (size_t)r0 * 256 + j0 + sc);
        if (r1 < re) nb1 = *(const uint4*)(Xm + (size_t)r1 * 256 + j0 + sc);
      }
    }
    __syncthreads();
    if (diag && mc) {
      const __half* p = ldsA + rp7(cc) * 36 + hh * 16;
#pragma unroll
      for (int k = 0; k < 16; ++k) xP += __half2float(p[k]);
    }
    f16x8 af[4];
#pragma unroll
    for (int fm = 0; fm < 4; ++fm) af[fm] = ldfrag(ldsA, wm * 64 + fm * 16 + lm, g);
#pragma unroll
    for (int fn = 0; fn < 4; ++fn) {
      f16x8 bf = ldfrag(Bsrc, wn * 64 + fn * 16 + lm, g);
#pragma unroll
      for (int fm = 0; fm < 4; ++fm)
        acc[fm][fn] = __builtin_amdgcn_mfma_f32_16x16x32_f16(af[fm], bf, acc[fm][fn], 0, 0, 0);
    }
    a0 = na0; a1 = na1; b0 = nb0; b1 = nb1;
  }
  float* pout = partial + (size_t)z * 65536;
#pragma unroll
  for (int fm = 0; fm < 4; ++fm) {
#pragma unroll
    for (int reg = 0; reg < 4; ++reg) {
      int row = i0 + wm * 64 + fm * 16 + g * 4 + reg;
#pragma unroll
      for (int fn = 0; fn < 4; ++fn) {
        int col = j0 + wn * 64 + fn * 16 + lm;
        pout[(size_t)row * 256 + col] = acc[fm][fn][reg];
      }
    }
  }
  if (diag && mc) {
    __syncthreads();
    float* fs = (float*)ldsA;
    fs[hh * 128 + cc] = xP;
    __syncthreads();
    if (tid < 128) atomicAdd(&mc[i0 + tid], (fs[tid] + fs[128 + tid]) * 16.0f); // *4^2
  }
}

__global__ void k_gram_reduce_sym(const float* __restrict__ partial, float* __restrict__ C) {
  int idx = blockIdx.x * 256 + threadIdx.x;
  int i = idx >> 8, j = idx & 255;
  int sidx = (i >= 128 && j < 128) ? (j * 256 + i) : idx;
  float s = 0.f;
  for (int z = 0; z < GRAM_KS; ++z) s += partial[(size_t)z * 65536 + sidx];
  C[idx] = s * 256.0f;    // *4^4
}

// ------- general Gram (fp16 in, MFMA, prefetched) + fused weighted colsums (*4^6) ----
__global__ __launch_bounds__(256) void k_gram(const __half* __restrict__ Xm,
    const __half* __restrict__ Ym, float* __restrict__ partial, int N,
    const float* __restrict__ wxA, const float* __restrict__ wxB, float* __restrict__ outX,
    const float* __restrict__ wyA, const float* __restrict__ wyB, float* __restrict__ outY) {
  __shared__ __half ldsA[128 * 36];
  __shared__ __half ldsB[128 * 36];
  __shared__ float wls[4][32];
  int tid = threadIdx.x;
  int i0 = blockIdx.x * 128, j0 = blockIdx.y * 128;
  int z = blockIdx.z;
  int chunk = (N + GRAM_KS - 1) / GRAM_KS;
  int rb = z * chunk, re = min(N, rb + chunk);
  int lane = tid & 63, w = tid >> 6;
  int g = lane >> 4;
  int lm = lane & 15;
  int wm = w >> 1, wn = w & 1;
  int sp = tid >> 4;
  int sc = (tid & 15) * 8;
  bool doX = (outX != nullptr) && (blockIdx.y == 0);
  bool doY = (outY != nullptr) && (blockIdx.x == 0);
  int cc = tid & 127, hh = tid >> 7;
  float xA = 0, xB = 0, xP = 0, yA = 0, yB = 0, yP = 0;
  f32x4 acc[4][4] = {};
  uint4 a0 = {0,0,0,0}, a1 = {0,0,0,0}, b0 = {0,0,0,0}, b1 = {0,0,0,0};
  {
    int r0 = rb + 2 * sp, r1 = r0 + 1;
    if (r0 < re) {
      a0 = *(const uint4*)(Xm + (size_t)r0 * 256 + i0 + sc);
      b0 = *(const uint4*)(Ym + (size_t)r0 * 256 + j0 + sc);
    }
    if (r1 < re) {
      a1 = *(const uint4*)(Xm + (size_t)r1 * 256 + i0 + sc);
      b1 = *(const uint4*)(Ym + (size_t)r1 * 256 + j0 + sc);
    }
  }
  for (int rr = rb; rr < re; rr += 32) {
    __syncthreads();
    {
      const unsigned short* pa0 = (const unsigned short*)&a0;
      const unsigned short* pa1 = (const unsigned short*)&a1;
      const unsigned short* pb0 = (const unsigned short*)&b0;
      const unsigned short* pb1 = (const unsigned short*)&b1;
#pragma unroll
      for (int j = 0; j < 8; ++j) {
        *(unsigned int*)(ldsA + rp7(sc + j) * 36 + 2 * sp) =
            (unsigned int)pa0[j] | ((unsigned int)pa1[j] << 16);
        *(unsigned int*)(ldsB + rp7(sc + j) * 36 + 2 * sp) =
            (unsigned int)pb0[j] | ((unsigned int)pb1[j] << 16);
      }
    }
    if (tid < 128) {
      int grp = tid >> 5, kk = tid & 31, rw = rr + kk;
      const float* wp = (grp == 0) ? wxA : (grp == 1) ? wxB : (grp == 2) ? wyA : wyB;
      wls[grp][kk] = (wp && rw < re) ? wp[rw] : 0.f;
    }
    // issue next tile's loads; in flight during colsum + MFMA
    uint4 na0 = {0,0,0,0}, na1 = {0,0,0,0}, nb0 = {0,0,0,0}, nb1 = {0,0,0,0};
    int nr = rr + 32;
    if (nr < re) {
      int r0 = nr + 2 * sp, r1 = r0 + 1;
      if (r0 < re) {
        na0 = *(const uint4*)(Xm + (size_t)r0 * 256 + i0 + sc);
        nb0 = *(const uint4*)(Ym + (size_t)r0 * 256 + j0 + sc);
      }
      if (r1 < re) {
        na1 = *(const uint4*)(Xm + (size_t)r1 * 256 + i0 + sc);
        nb1 = *(const uint4*)(Ym + (size_t)r1 * 256 + j0 + sc);
      }
    }
    __syncthreads();
    if (doX) {
      const __half* p = ldsA + rp7(cc) * 36 + hh * 16;
#pragma unroll
      for (int k = 0; k < 16; ++k) {
        float v = __half2float(p[k]);
        xP += v; xA += v * wls[0][hh * 16 + k]; xB += v * wls[1][hh * 16 + k];
      }
    }
    if (doY) {
      const __half* p = ldsB + rp7(cc) * 36 + hh * 16;
#pragma unroll
      for (int k = 0; k < 16; ++k) {
        float v = __half2float(p[k]);
        yP += v; yA += v * wls[2][hh * 16 + k]; yB += v * wls[3][hh * 16 + k];
      }
    }
    f16x8 af[4];
#pragma unroll
    for (int fm = 0; fm < 4; ++fm) af[fm] = ldfrag(ldsA, wm * 64 + fm * 16 + lm, g);
#pragma unroll
    for (int fn = 0; fn < 4; ++fn) {
      f16x8 bf = ldfrag(ldsB, wn * 64 + fn * 16 + lm, g);
#pragma unroll
      for (int fm = 0; fm < 4; ++fm)
        acc[fm][fn] = __builtin_amdgcn_mfma_f32_16x16x32_f16(af[fm], bf, acc[fm][fn], 0, 0, 0);
    }
    a0 = na0; a1 = na1; b0 = nb0; b1 = nb1;
  }
  float* pout = partial + (size_t)z * 65536;
#pragma unroll
  for (int fm = 0; fm < 4; ++fm) {
#pragma unroll
    for (int reg = 0; reg < 4; ++reg) {
      int row = i0 + wm * 64 + fm * 16 + g * 4 + reg;
#pragma unroll
      for (int fn = 0; fn < 4; ++fn) {
        int col = j0 + wn * 64 + fn * 16 + lm;
        pout[(size_t)row * 256 + col] = acc[fm][fn][reg];
      }
    }
  }
  const float S6 = 4096.0f;   // 4^6
  float* fs = (float*)ldsA;
  if (doX) {
    __syncthreads();
    fs[hh * 128 + cc] = xA;
    __syncthreads();
    if (tid < 128) atomicAdd(&outX[i0 + tid], (fs[tid] + fs[128 + tid]) * S6);
    __syncthreads();
    fs[hh * 128 + cc] = xB;
    __syncthreads();
    if (tid < 128) atomicAdd(&outX[256 + i0 + tid], (fs[tid] + fs[128 + tid]) * S6);
    __syncthreads();
    fs[hh * 128 + cc] = xP;
    __syncthreads();
    if (tid < 128) atomicAdd(&outX[512 + i0 + tid], (fs[tid] + fs[128 + tid]) * S6);
  }
  if (doY) {
    __syncthreads();
    fs[hh * 128 + cc] = yA;
    __syncthreads();
    if (tid < 128) atomicAdd(&outY[j0 + tid], (fs[tid] + fs[128 + tid]) * S6);
    __syncthreads();
    fs[hh * 128 + cc] = yB;
    __syncthreads();
    if (tid < 128) atomicAdd(&outY[256 + j0 + tid], (fs[tid] + fs[128 + tid]) * S6);
    __syncthreads();
    fs[hh * 128 + cc] = yP;
    __syncthreads();
    if (tid < 128) atomicAdd(&outY[512 + j0 + tid], (fs[tid] + fs[128 + tid]) * S6);
  }
}

__global__ void k_gram_reduce(const float* __restrict__ partial, float* __restrict__ C) {
  int idx = blockIdx.x * 256 + threadIdx.x;
  float s = 0.f;
  for (int z = 0; z < GRAM_KS; ++z) s += partial[(size_t)z * 65536 + idx];
  C[idx] = s * 16777216.0f;   // *4^12
}

// ---------------- 8 scalar reductions over d/e vectors ----------------
// grid-stride, per-block LDS reduce, one atomic per block per counter
__global__ __launch_bounds__(256) void k_dots(const float* __restrict__ d1,
    const float* __restrict__ e1, const float* __restrict__ d2,
    const float* __restrict__ e2, float* scal, int n) {
  float s[8] = {};
  for (int i = blockIdx.x * 256 + threadIdx.x; i < n; i += gridDim.x * 256) {
    float a = d1[i], b = e1[i], c = d2[i], d = e2[i];
    s[0] += b * d; s[1] += b * c; s[2] += b; s[3] += a * d;
    s[4] += a * c; s[5] += a; s[6] += d; s[7] += c;
  }
  __shared__ float red[4][8];
  int lane = threadIdx.x & 63, w = threadIdx.x >> 6;
#pragma unroll
  for (int j = 0; j < 8; ++j)
    for (int off = 32; off; off >>= 1) s[j] += __shfl_down(s[j], off);
  if (lane == 0)
#pragma unroll
    for (int j = 0; j < 8; ++j) red[w][j] = s[j];
  __syncthreads();
  if (threadIdx.x < 8) {
    int j = threadIdx.x;
    atomicAdd(&scal[j], red[0][j] + red[1][j] + red[2][j] + red[3][j]);
  }
}

// ---------------- t_j = w_j^T C w_j ; mv_j = w_j . m_raw ----------------
__global__ __launch_bounds__(256) void k_quad(const float* __restrict__ C,
    const float* __restrict__ W1, const float* __restrict__ m_raw,
    float* __restrict__ t, float* __restrict__ mv) {
  __shared__ float w[256];
  __shared__ float r1[256], r2[256];
  int j = blockIdx.x, tid = threadIdx.x;
  w[tid] = W1[j * 256 + tid];
  __syncthreads();
  float v = 0.f;
  for (int k = 0; k < 256; ++k) v += w[k] * C[k * 256 + tid];
  r1[tid] = v * w[tid];
  r2[tid] = w[tid] * m_raw[tid];
  __syncthreads();
  for (int off = 128; off; off >>= 1) {
    if (tid < off) { r1[tid] += r1[tid + off]; r2[tid] += r2[tid + off]; }
    __syncthreads();
  }
  if (tid == 0) { t[j] = r1[0]; mv[j] = r2[0]; }
}

// ---------------- BN coefficients (coalesced W2T/W3T) ----------------
__global__ __launch_bounds__(256) void k_bncoef(const float* __restrict__ t,
    const float* __restrict__ mv, const float* __restrict__ b1,
    const float* __restrict__ gamma, const float* __restrict__ beta,
    const float* __restrict__ W2T, const float* __restrict__ W3T,
    const float* __restrict__ b2, float* Dv, float* xv, float* yv, int n) {
  __shared__ float c[256], u[256];
  int j = threadIdx.x;
  float invn = 1.f / (float)n;
  float mean = mv[j] * invn + b1[j];
  float E2 = t[j] * invn + 2.f * b1[j] * mv[j] * invn + b1[j] * b1[j];
  float var = E2 - mean * mean;
  float D = gamma[j] * rsqrtf(var + 1e-5f);
  Dv[j] = D;
  c[j] = D * (b1[j] - mean) + beta[j];
  __syncthreads();
  float uu = 0.f;
  for (int k = 0; k < 256; ++k) uu += W2T[k * 256 + j] * c[k];
  u[j] = uu;
  __syncthreads();
  float xx = 0.f, yy = 0.f;
  for (int k = 0; k < 256; ++k) {
    xx += W3T[k * 256 + j] * u[k];
    yy += W3T[k * 256 + j] * b2[k];
  }
  xv[j] = xx;
  yv[j] = yy;
}

// ---------------- small 256x256 matmul (B coalesced) ----------------
__global__ __launch_bounds__(256) void k_mm_small(float* __restrict__ Cm,
    const float* __restrict__ A, const float* __restrict__ B,
    const float* __restrict__ s, int transA) {
  __shared__ float a[256];
  int i = blockIdx.x, j = threadIdx.x;
  float av = transA ? A[j * 256 + i] : A[i * 256 + j];
  a[j] = s ? av * s[j] : av;
  __syncthreads();
  float acc = 0.f;
  for (int k = 0; k < 256; ++k) acc += a[k] * B[k * 256 + j];
  Cm[i * 256 + j] = acc;
}

// ---------------- 6 matvecs ----------------
__global__ __launch_bounds__(256) void k_mv6(const float* __restrict__ R1,
    const float* __restrict__ R2, const float* __restrict__ pX,
    const float* __restrict__ qY, float* __restrict__ vout) {
  __shared__ float w[256];
  int b = blockIdx.x, j = threadIdx.x;
  const float* M = (b < 3) ? R1 : R2;
  const float* wv = (b < 3) ? (pX + b * 256) : (qY + (b - 3) * 256);
  w[j] = wv[j];
  __syncthreads();
  float s = 0.f;
  for (int k = 0; k < 256; ++k) s += M[k * 256 + j] * w[k];
  vout[b * 256 + j] = s;
}

// ---------------- final ----------------
__global__ __launch_bounds__(256) void k_mm_final(float* __restrict__ out,
    const float* __restrict__ R1, const float* __restrict__ T1,
    const float* __restrict__ vout,
    const float* __restrict__ x1, const float* __restrict__ x2,
    const float* __restrict__ yv, const float* __restrict__ b3,
    const float* __restrict__ scal, float fN) {
  __shared__ float a[256];
  int i = blockIdx.x, j = threadIdx.x;
  a[j] = R1[j * 256 + i];
  __syncthreads();
  float acc = 0.f;
  for (int k = 0; k < 256; ++k) acc += a[k] * T1[k * 256 + j];
  float s1 = scal[0] * x2[j] + scal[1] * yv[j] + scal[2] * b3[j];
  float s2 = scal[3] * x2[j] + scal[4] * yv[j] + scal[5] * b3[j];
  float s3 = scal[6] * x2[j] + scal[7] * yv[j] + fN * b3[j];
  acc += vout[i] * x2[j] + vout[256 + i] * yv[j] + vout[512 + i] * b3[j];
  acc += x1[i] * (vout[768 + j] + s1) + yv[i] * (vout[1024 + j] + s2)
       + b3[i] * (vout[1280 + j] + s3);
  out[i * 256 + j] = acc;
}

extern "C" void kernel_launch(void* const* d_in, const int* in_sizes, int n_in,
                              void* d_out, int out_size, void* d_ws, size_t ws_size,
                              hipStream_t stream) {
  const float* feature = (const float*)d_in[0];
  const int* src1 = (const int*)d_in[1];
  const int* dst1 = (const int*)d_in[2];
  const int* src2 = (const int*)d_in[3];
  const int* dst2 = (const int*)d_in[4];
  const float* W1 = (const float*)d_in[5];
  const float* b1 = (const float*)d_in[6];
  const float* W2 = (const float*)d_in[7];
  const float* b2 = (const float*)d_in[8];
  const float* W3 = (const float*)d_in[9];
  const float* b3 = (const float*)d_in[10];
  const float* gamma = (const float*)d_in[11];
  const float* beta = (const float*)d_in[12];
  const int N = in_sizes[0] / FDIM;
  const int E = in_sizes[1];
  float* out = (float*)d_out;

  // ---- workspace layout (fp16 tables + dedicated fp32 partial) ----
  size_t NF = (size_t)N * FDIM;
  __half* FH = (__half*)d_ws;
  __half* Xh = FH + NF;
  __half* Yh = Xh + NF;
  __half* G2A = Yh + NF;
  float* partial = (float*)(G2A + NF);
  int* rowptr1 = (int*)(partial + (size_t)GRAM_KS * 65536);
  int* rowptr2 = rowptr1 + (N + 1);
  int* cursor = rowptr2 + (N + 1);
  int* esrc1 = cursor + N;
  int* esrc2 = esrc1 + E;
  float* vtmp1 = (float*)(esrc2 + E);
  float* vtmp2 = vtmp1 + N;
  float* d1 = vtmp2 + N; float* e1 = d1 + N; float* d2 = e1 + N; float* e2 = d2 + N;
  float* C = e2 + N;
  float* mcA = C + 65536;            // zeroed span start
  float* mcB = mcA + 256;
  float* pX = mcB + 256;
  float* qY = pX + 768;
  float* scal = qY + 768;
  float* tq = scal + 16; float* mv = tq + 256;
  float* Dv = mv + 256; float* x1 = Dv + 256; float* x2 = x1 + 256; float* yv = x2 + 256;
  float* Q = yv + 256; float* R1 = Q + 65536; float* R2 = R1 + 65536;
  float* Z = R2 + 65536; float* T1 = Z + 65536;
  float* W2T = T1 + 65536; float* W3T = W2T + 65536;
  float* vout = W3T + 65536;
  int* blksum = (int*)(vout + 1536);
  int* blkoff = blksum + 1024;
  int* gcur = blkoff + 1024;
  int2* pairs = (int2*)partial;      // scratch during CSR build (before grams)

  const int eb = (E + 255) / 256;
  const int avb2 = (2 * N * 16 + 255) / 256;
  const int nblk = (N + 1023) / 1024;
  int bshift = 0;
  while (((N - 1) >> bshift) >= NB) ++bshift;
  const int nbk = ((N - 1) >> bshift) + 1;
  const int pb = (E + 4095) / 4096;
  const int aggb = 2048;             // persistent: 8 blocks/CU, grid-stride over nodes

  auto build = [&](const int* s_, const int* d_, int* rp, int* es) {
    hipMemsetAsync(cursor, 0, (size_t)N * sizeof(int), stream);
    k_hist<<<eb, 256, 0, stream>>>(d_, cursor, E);
    k_blksum<<<nblk, 256, 0, stream>>>(cursor, blksum, N);
    k_blkscan<<<1, 64, 0, stream>>>(blksum, blkoff, nblk);
    k_scan_blk<<<nblk, 256, 0, stream>>>(cursor, blkoff, rp, cursor, N);
    k_binit<<<1, 64, 0, stream>>>(rp, gcur, N, bshift);
    k_part<<<pb, 256, 0, stream>>>(s_, d_, gcur, pairs, E, bshift);
    k_scat2<<<nbk, 512, 0, stream>>>(pairs, rp, cursor, es, N, bshift);
  };

  k_tr2<<<dim3(4, 4, 2), 256, 0, stream>>>(W2, W3, W2T, W3T);
  k_f2h<<<(int)((NF / 4 + 255) / 256), 256, 0, stream>>>(feature, FH, (int)(NF / 4));
  build(src1, dst1, rowptr1, esrc1);
  build(src2, dst2, rowptr2, esrc2);
  hipMemsetAsync(mcA, 0, (256 * 2 + 768 * 2 + 16) * sizeof(float), stream);

  // ---- d/e vectors (fp32, exact) ----
  k_aggv2<<<avb2, 256, 0, stream>>>(nullptr, nullptr, rowptr1, esrc1, rowptr2, esrc2,
                                    d1, d2, N, 1);
  k_aggv2<<<avb2, 256, 0, stream>>>(d1, d2, rowptr1, esrc1, rowptr2, esrc2,
                                    vtmp1, vtmp2, N, 0);
  k_aggv2<<<avb2, 256, 0, stream>>>(vtmp1, vtmp2, rowptr1, esrc1, rowptr2, esrc2,
                                    e1, e2, N, 0);
  k_dots<<<64, 256, 0, stream>>>(d1, e1, d2, e2, scal, N);

  auto do_branch = [&](const int* rp, const int* es, __half* G2dst,
                       float* mc, float* xvec, float* Rdst) {
    k_aggh<<<aggb, 256, 0, stream>>>(FH, rp, es, Xh, N);
    k_aggh<<<aggb, 256, 0, stream>>>(Xh, rp, es, Yh, N);              // Yh = G0/16
    k_gram_sym<<<dim3(3, 1, GRAM_KS), 256, 0, stream>>>(Yh, partial, N, mc);
    k_gram_reduce_sym<<<256, 256, 0, stream>>>(partial, C);           // C true scale
    k_quad<<<256, 256, 0, stream>>>(C, W1, mc, tq, mv);
    k_bncoef<<<1, 256, 0, stream>>>(tq, mv, b1, gamma, beta, W2T, W3T, b2, Dv, xvec, yv, N);
    k_mm_small<<<256, 256, 0, stream>>>(Q, W1, W2T, Dv, 1);
    k_mm_small<<<256, 256, 0, stream>>>(Rdst, Q, W3T, nullptr, 0);
    k_aggh<<<aggb, 256, 0, stream>>>(Yh, rp, es, Xh, N);
    k_aggh<<<aggb, 256, 0, stream>>>(Xh, rp, es, Yh, N);              // A^4 F /256
    k_aggh<<<aggb, 256, 0, stream>>>(Yh, rp, es, Xh, N);
    k_aggh<<<aggb, 256, 0, stream>>>(Xh, rp, es, G2dst, N);           // G2/4096
  };

  do_branch(rowptr1, esrc1, G2A, mcA, x1, R1);
  do_branch(rowptr2, esrc2, Yh, mcB, x2, R2);   // branch-2 G2 lands in Yh

  // ---- final: Z = G2_1^T G2_2 (rescaled) + fused weighted colsums ----
  k_gram<<<dim3(2, 2, GRAM_KS), 256, 0, stream>>>(G2A, Yh, partial, N,
      e2, d2, pX, e1, d1, qY);
  k_gram_reduce<<<256, 256, 0, stream>>>(partial, Z);

  k_mm_small<<<256, 256, 0, stream>>>(T1, Z, R2, nullptr, 0);
  k_mv6<<<6, 256, 0, stream>>>(R1, R2, pX, qY, vout);
  k_mm_final<<<256, 256, 0, stream>>>(out, R1, T1, vout, x1, x2, yv, b3, scal, (float)N);
}

// Round 12
// 1269.327 us; speedup vs baseline: 1.0639x; 1.0639x over previous
//
#include <hip/hip_runtime.h>
#include <hip/hip_fp16.h>

#define FDIM 256
#define GRAM_KS 192
#define NB 64

// scaled-fp16 storage: hop h stored = true * 4^-h. Rescales (exact powers of 2):
//   C = G0^T G0: *256 ; Z = G2^T G2: *2^24 ; G2 colsums: *4096 ; G0 colsum: *16

typedef _Float16 f16x8 __attribute__((ext_vector_type(8)));
typedef float f32x4 __attribute__((ext_vector_type(4)));
typedef unsigned int u32x4 __attribute__((ext_vector_type(4)));

union H8 { uint2 u2[2]; f16x8 v; };

// LDS row permutation: kills the 8-way bank conflict of the staging write
// (rows 8t+j at word-col sp: 8*18 words == 16 mod 32 -> 2 banks). perm mixes
// c>>3 into the low bits; both writes and ldfrag b64 reads become conflict-free
// (bank = 18*perm(c) mod 32 distinct over each 16-lane group); alignment kept.
__device__ __forceinline__ int rp7(int c) { return c ^ (c >> 3); }

// load an 8-half MFMA operand fragment from permuted-row LDS tile ldsT[perm(col)][36]
// lane group g = (lane>>4)&3 ; k-slots: {g*4..g*4+3, 16+g*4..16+g*4+3}
// (same k-map used for A and B -> any consistent bijection is valid)
__device__ __forceinline__ f16x8 ldfrag(const __half* ldsT, int m, int g) {
  H8 h;
  const __half* row = ldsT + rp7(m) * 36;
  h.u2[0] = *(const uint2*)(row + g * 4);
  h.u2[1] = *(const uint2*)(row + 16 + g * 4);
  return h.v;
}

__device__ __forceinline__ void h8acc(uint4 u, float* a) {
  float2 t;
  t = __half22float2(*(__half2*)&u.x); a[0] += t.x; a[1] += t.y;
  t = __half22float2(*(__half2*)&u.y); a[2] += t.x; a[3] += t.y;
  t = __half22float2(*(__half2*)&u.z); a[4] += t.x; a[5] += t.y;
  t = __half22float2(*(__half2*)&u.w); a[6] += t.x; a[7] += t.y;
}

// ---------------- CSR build ----------------
__global__ void k_hist(const int* __restrict__ dst, int* __restrict__ deg, int E) {
  int e = blockIdx.x * 256 + threadIdx.x;
  if (e < E) atomicAdd(&deg[dst[e]], 1);
}

__global__ __launch_bounds__(256) void k_blksum(const int* __restrict__ deg,
    int* __restrict__ blksum, int n) {
  int b = blockIdx.x, tid = threadIdx.x;
  int base = b * 1024 + tid * 4;
  int s = 0;
#pragma unroll
  for (int k = 0; k < 4; ++k) if (base + k < n) s += deg[base + k];
  for (int off = 32; off; off >>= 1) s += __shfl_down(s, off);
  __shared__ int ws4[4];
  if ((tid & 63) == 0) ws4[tid >> 6] = s;
  __syncthreads();
  if (tid == 0) blksum[b] = ws4[0] + ws4[1] + ws4[2] + ws4[3];
}

__global__ void k_blkscan(const int* __restrict__ blksum, int* __restrict__ blkoff, int nblk) {
  int lane = threadIdx.x;
  int carry = 0;
  for (int base = 0; base < nblk; base += 64) {
    int v = (base + lane < nblk) ? blksum[base + lane] : 0;
    int x = v;
    for (int off = 1; off < 64; off <<= 1) { int y = __shfl_up(x, off); if (lane >= off) x += y; }
    if (base + lane < nblk) blkoff[base + lane] = carry + x - v;
    carry += __shfl(x, 63);
  }
}

__global__ __launch_bounds__(256) void k_scan_blk(const int* __restrict__ deg,
    const int* __restrict__ blkoff, int* __restrict__ rowptr, int* __restrict__ cursor, int n) {
  int b = blockIdx.x, tid = threadIdx.x;
  int base = b * 1024 + tid * 4;
  int v[4];
#pragma unroll
  for (int k = 0; k < 4; ++k) v[k] = (base + k < n) ? deg[base + k] : 0;
  int s = v[0] + v[1] + v[2] + v[3];
  int lane = tid & 63, w = tid >> 6;
  int x = s;
  for (int off = 1; off < 64; off <<= 1) { int y = __shfl_up(x, off); if (lane >= off) x += y; }
  __shared__ int wsum[4];
  if (lane == 63) wsum[w] = x;
  __syncthreads();
  int wadd = 0;
  for (int i = 0; i < w; ++i) wadd += wsum[i];
  int run = blkoff[b] + wadd + x - s;
#pragma unroll
  for (int k = 0; k < 4; ++k) {
    if (base + k < n) { rowptr[base + k] = run; cursor[base + k] = run; }
    run += v[k];
  }
  if (n >= base && n <= base + 4) rowptr[n] = run;
}

// ---------------- two-phase scatter ----------------
__global__ void k_binit(const int* __restrict__ rowptr, int* __restrict__ gcur,
    int N, int bshift) {
  int b = threadIdx.x;
  if (b < NB) {
    int idx = b << bshift;
    if (idx > N) idx = N;
    gcur[b] = rowptr[idx];
  }
}

// Phase A: partition edges into NB dst-range buckets; per-block LDS staging so
// global writes are long contiguous runs per bucket (no line-sharing amplification)
__global__ __launch_bounds__(256) void k_part(const int* __restrict__ src,
    const int* __restrict__ dst, int* __restrict__ gcur, int2* __restrict__ pairs,
    int E, int bshift) {
  __shared__ int cnt[NB];
  __shared__ int lbase[NB];
  __shared__ int gbase[NB];
  __shared__ int tot;
  __shared__ int2 stg[4096];
  int tid = threadIdx.x;
  int e0 = blockIdx.x * 4096;
  if (tid < NB) cnt[tid] = 0;
  __syncthreads();
  int es[16], ed[16], lp[16];
#pragma unroll
  for (int k = 0; k < 16; ++k) {
    int e = e0 + k * 256 + tid;
    lp[k] = -1;
    if (e < E) {
      es[k] = src[e]; ed[k] = dst[e];
      lp[k] = atomicAdd(&cnt[ed[k] >> bshift], 1);
    }
  }
  __syncthreads();
  if (tid < NB) {
    int v = cnt[tid];
    int x = v;
    for (int off = 1; off < NB; off <<= 1) { int y = __shfl_up(x, off); if (tid >= off) x += y; }
    lbase[tid] = x - v;
    gbase[tid] = atomicAdd(&gcur[tid], v);
    if (tid == NB - 1) tot = x;
  }
  __syncthreads();
#pragma unroll
  for (int k = 0; k < 16; ++k) {
    if (lp[k] >= 0) stg[lbase[ed[k] >> bshift] + lp[k]] = make_int2(es[k], ed[k]);
  }
  __syncthreads();
  int T = tot;
  for (int i = tid; i < T; i += 256) {
    int2 p = stg[i];
    int b = p.y >> bshift;
    pairs[gbase[b] + (i - lbase[b])] = p;
  }
}

// Phase B: one block per bucket; scatter confined to one small region (one XCD's L2)
__global__ __launch_bounds__(512) void k_scat2(const int2* __restrict__ pairs,
    const int* __restrict__ rowptr, int* __restrict__ cursor, int* __restrict__ esrc,
    int N, int bshift) {
  int b = blockIdx.x;
  int i0 = b << bshift, i1 = (b + 1) << bshift;
  if (i0 > N) i0 = N;
  if (i1 > N) i1 = N;
  int lo = rowptr[i0], hi = rowptr[i1];
  for (int i = lo + threadIdx.x; i < hi; i += 512) {
    int2 p = pairs[i];
    int pos = atomicAdd(&cursor[p.y], 1);
    esrc[pos] = p.x;
  }
}

// ---------------- transpose W2,W3 ----------------
__global__ __launch_bounds__(256) void k_tr2(const float* __restrict__ W2,
    const float* __restrict__ W3, float* __restrict__ W2T, float* __restrict__ W3T) {
  __shared__ float tile[64][65];
  const float* src = blockIdx.z ? W3 : W2;
  float* dst = blockIdx.z ? W3T : W2T;
  int i0 = blockIdx.x * 64, j0 = blockIdx.y * 64;
  int tx = threadIdx.x & 63, ty = threadIdx.x >> 6;
#pragma unroll
  for (int m = 0; m < 16; ++m) {
    int r = ty * 16 + m;
    tile[r][tx] = src[(size_t)(i0 + r) * 256 + j0 + tx];
  }
  __syncthreads();
#pragma unroll
  for (int m = 0; m < 16; ++m) {
    int r = ty * 16 + m;
    dst[(size_t)(j0 + r) * 256 + i0 + tx] = tile[tx][r];
  }
}

// ---------------- feature -> fp16 ----------------
__global__ __launch_bounds__(256) void k_f2h(const float* __restrict__ F,
    __half* __restrict__ H, int n4) {
  int i = blockIdx.x * 256 + threadIdx.x;
  if (i >= n4) return;
  float4 v = ((const float4*)F)[i];
  __half2 a = __floats2half2_rn(v.x, v.y);
  __half2 b = __floats2half2_rn(v.z, v.w);
  uint2 u; u.x = *(unsigned int*)&a; u.y = *(unsigned int*)&b;
  ((uint2*)H)[i] = u;
}

// ---------------- fp16 aggregation: one wave/node, 2 edges x unroll-4 in flight ----
// lane loads uint4 (8 halves); 32 lanes cover a 256-col row; half-waves take
// alternating edges; final __shfl_xor(32) combines. out = sum/4 (nontemporal store
// so the 25.6MB output doesn't evict the gather table from L2).
__global__ __launch_bounds__(256) void k_aggh(const __half* __restrict__ h,
    const int* __restrict__ rowptr, const int* __restrict__ esrc,
    __half* __restrict__ out, int n) {
  int wid = ((blockIdx.x * 256) + threadIdx.x) >> 6;
  int lane = threadIdx.x & 63;
  if (wid >= n) return;
  int half = lane >> 5, l5 = lane & 31;
  int beg = rowptr[wid], end = rowptr[wid + 1];
  int m = end - beg;
  const uint4* hv = (const uint4*)h;     // row = 32 x uint4 (8 halves each)
  float a0[8] = {}, a1[8] = {}, a2[8] = {}, a3[8] = {};
  int g8 = m >> 3;
  int e = beg + half;
  for (int it = 0; it < g8; ++it, e += 8) {
    int s0 = esrc[e], s1 = esrc[e + 2], s2 = esrc[e + 4], s3 = esrc[e + 6];
    uint4 u0 = hv[(size_t)s0 * 32 + l5];
    uint4 u1 = hv[(size_t)s1 * 32 + l5];
    uint4 u2 = hv[(size_t)s2 * 32 + l5];
    uint4 u3 = hv[(size_t)s3 * 32 + l5];
    h8acc(u0, a0); h8acc(u1, a1); h8acc(u2, a2); h8acc(u3, a3);
  }
  for (; e < end; e += 2) {
    uint4 u = hv[(size_t)esrc[e] * 32 + l5];
    h8acc(u, a0);
  }
  float s[8];
#pragma unroll
  for (int j = 0; j < 8; ++j) {
    s[j] = (a0[j] + a1[j]) + (a2[j] + a3[j]);
    s[j] += __shfl_xor(s[j], 32);
    s[j] *= 0.25f;
  }
  if (half == 0) {
    __half2 h0 = __floats2half2_rn(s[0], s[1]);
    __half2 h1 = __floats2half2_rn(s[2], s[3]);
    __half2 h2 = __floats2half2_rn(s[4], s[5]);
    __half2 h3 = __floats2half2_rn(s[6], s[7]);
    u32x4 uo;
    uo.x = *(unsigned int*)&h0; uo.y = *(unsigned int*)&h1;
    uo.z = *(unsigned int*)&h2; uo.w = *(unsigned int*)&h3;
    __builtin_nontemporal_store(uo, (u32x4*)out + (size_t)wid * 32 + l5);
  }
}

// ---------------- dual-graph scalar aggregation (fp32, exact) ----------------
__global__ __launch_bounds__(256) void k_aggv2(const float* __restrict__ in1,
    const float* __restrict__ in2,
    const int* __restrict__ rp1, const int* __restrict__ es1,
    const int* __restrict__ rp2, const int* __restrict__ es2,
    float* __restrict__ out1, float* __restrict__ out2, int n, int useDeg) {
  int t = blockIdx.x * 256 + threadIdx.x;
  int g = t >> 4;
  int sl = t & 15;
  if (g >= 2 * n) return;
  int which = (g >= n) ? 1 : 0;
  int node = which ? g - n : g;
  const int* rp = which ? rp2 : rp1;
  const int* es = which ? es2 : es1;
  const float* in = which ? in2 : in1;
  float* out = which ? out2 : out1;
  int beg = rp[node], end = rp[node + 1];
  float s = 0.f;
  if (useDeg) {
    for (int e = beg + sl; e < end; e += 16) {
      int v = es[e];
      s += (float)(rp[v + 1] - rp[v]);
    }
  } else {
    for (int e = beg + sl; e < end; e += 16) s += in[es[e]];
  }
#pragma unroll
  for (int off = 8; off; off >>= 1) s += __shfl_down(s, off, 16);
  if (sl == 0) out[node] = s;
}

// ---------------- symmetric Gram on fp16 input (MFMA, prefetched staging) -------
// C-tile 128x128 per block, 4 waves in 2x2, each wave 64x64 via 16x16x32 f16 MFMA.
// LDS holds transposed tiles ldsT[perm(col)][k]; next tile's global loads issue
// before the MFMA phase so L3 latency hides under compute.
__global__ __launch_bounds__(256) void k_gram_sym(const __half* __restrict__ Xm,
    float* __restrict__ partial, int N, float* __restrict__ mc) {
  __shared__ __half ldsA[128 * 36];
  __shared__ __half ldsB[128 * 36];
  int tid = threadIdx.x;
  int t = blockIdx.x;                       // 0:(0,0) 1:(0,1) 2:(1,1)
  int i0 = (t == 2) ? 128 : 0;
  int j0 = (t == 0) ? 0 : 128;
  bool diag = (t != 1);
  int z = blockIdx.z;
  int chunk = (N + GRAM_KS - 1) / GRAM_KS;
  int rb = z * chunk, re = min(N, rb + chunk);
  int lane = tid & 63, w = tid >> 6;
  int g = lane >> 4;
  int lm = lane & 15;
  int wm = w >> 1, wn = w & 1;
  int sp = tid >> 4;                         // staging row-pair 0..15
  int sc = (tid & 15) * 8;                   // staging col offset
  int cc = tid & 127, hh = tid >> 7;
  float xP = 0.f;
  f32x4 acc[4][4] = {};
  const __half* Bsrc = diag ? ldsA : ldsB;
  uint4 a0 = {0,0,0,0}, a1 = {0,0,0,0}, b0 = {0,0,0,0}, b1 = {0,0,0,0};
  {
    int r0 = rb + 2 * sp, r1 = r0 + 1;
    if (r0 < re) a0 = *(const uint4*)(Xm + (size_t)r0 * 256 + i0 + sc);
    if (r1 < re) a1 = *(const uint4*)(Xm + (size_t)r1 * 256 + i0 + sc);
    if (!diag) {
      if (r0 < re) b0 = *(const uint4*)(Xm + (size_t)r0 * 256 + j0 + sc);
      if (r1 < re) b1 = *(const uint4*)(Xm + (size_t)r1 * 256 + j0 + sc);
    }
  }
  for (int rr = rb; rr < re; rr += 32) {
    __syncthreads();   // previous-iter LDS reads done
    {
      const unsigned short* pa0 = (const unsigned short*)&a0;
      const unsigned short* pa1 = (const unsigned short*)&a1;
      const unsigned short* pb0 = (const unsigned short*)&b0;
      const unsigned short* pb1 = (const unsigned short*)&b1;
#pragma unroll
      for (int j = 0; j < 8; ++j) {
        *(unsigned int*)(ldsA + rp7(sc + j) * 36 + 2 * sp) =
            (unsigned int)pa0[j] | ((unsigned int)pa1[j] << 16);
        if (!diag)
          *(unsigned int*)(ldsB + rp7(sc + j) * 36 + 2 * sp) =
              (unsigned int)pb0[j] | ((unsigned int)pb1[j] << 16);
      }
    }
    // issue next tile's loads now; they fly under the MFMA phase
    uint4 na0 = {0,0,0,0}, na1 = {0,0,0,0}, nb0 = {0,0,0,0}, nb1 = {0,0,0,0};
    int nr = rr + 32;
    if (nr < re) {
      int r0 = nr + 2 * sp, r1 = r0 + 1;
      if (r0 < re) na0 = *(const uint4*)(Xm + (size_t)r0 * 256 + i0 + sc);
      if (r1 < re) na1 = *(const uint4*)(Xm + (size_t)r1 * 256 + i0 + sc);
      if (!diag) {
        if (r0 < re) nb0 = *(const uint4*)(Xm + (size_t)r0 * 256 + j0 + sc);
        if (r1 < re) nb1 = *(const uint4*)(Xm + (size_t)r1 * 256 + j0 + sc);
      }
    }
    __syncthreads();
    if (diag && mc) {
      const __half* p = ldsA + rp7(cc) * 36 + hh * 16;
#pragma unroll
      for (int k = 0; k < 16; ++k) xP += __half2float(p[k]);
    }
    f16x8 af[4];
#pragma unroll
    for (int fm = 0; fm < 4; ++fm) af[fm] = ldfrag(ldsA, wm * 64 + fm * 16 + lm, g);
#pragma unroll
    for (int fn = 0; fn < 4; ++fn) {
      f16x8 bf = ldfrag(Bsrc, wn * 64 + fn * 16 + lm, g);
#pragma unroll
      for (int fm = 0; fm < 4; ++fm)
        acc[fm][fn] = __builtin_amdgcn_mfma_f32_16x16x32_f16(af[fm], bf, acc[fm][fn], 0, 0, 0);
    }
    a0 = na0; a1 = na1; b0 = nb0; b1 = nb1;
  }
  float* pout = partial + (size_t)z * 65536;
#pragma unroll
  for (int fm = 0; fm < 4; ++fm) {
#pragma unroll
    for (int reg = 0; reg < 4; ++reg) {
      int row = i0 + wm * 64 + fm * 16 + g * 4 + reg;
#pragma unroll
      for (int fn = 0; fn < 4; ++fn) {
        int col = j0 + wn * 64 + fn * 16 + lm;
        pout[(size_t)row * 256 + col] = acc[fm][fn][reg];
      }
    }
  }
  if (diag && mc) {
    __syncthreads();
    float* fs = (float*)ldsA;
    fs[hh * 128 + cc] = xP;
    __syncthreads();
    if (tid < 128) atomicAdd(&mc[i0 + tid], (fs[tid] + fs[128 + tid]) * 16.0f); // *4^2
  }
}

__global__ void k_gram_reduce_sym(const float* __restrict__ partial, float* __restrict__ C) {
  int idx = blockIdx.x * 256 + threadIdx.x;
  int i = idx >> 8, j = idx & 255;
  int sidx = (i >= 128 && j < 128) ? (j * 256 + i) : idx;
  float s = 0.f;
  for (int z = 0; z < GRAM_KS; ++z) s += partial[(size_t)z * 65536 + sidx];
  C[idx] = s * 256.0f;    // *4^4
}

// ------- general Gram (fp16 in, MFMA, prefetched) + fused weighted colsums (*4^6) ----
__global__ __launch_bounds__(256) void k_gram(const __half* __restrict__ Xm,
    const __half* __restrict__ Ym, float* __restrict__ partial, int N,
    const float* __restrict__ wxA, const float* __restrict__ wxB, float* __restrict__ outX,
    const float* __restrict__ wyA, const float* __restrict__ wyB, float* __restrict__ outY) {
  __shared__ __half ldsA[128 * 36];
  __shared__ __half ldsB[128 * 36];
  __shared__ float wls[4][32];
  int tid = threadIdx.x;
  int i0 = blockIdx.x * 128, j0 = blockIdx.y * 128;
  int z = blockIdx.z;
  int chunk = (N + GRAM_KS - 1) / GRAM_KS;
  int rb = z * chunk, re = min(N, rb + chunk);
  int lane = tid & 63, w = tid >> 6;
  int g = lane >> 4;
  int lm = lane & 15;
  int wm = w >> 1, wn = w & 1;
  int sp = tid >> 4;
  int sc = (tid & 15) * 8;
  bool doX = (outX != nullptr) && (blockIdx.y == 0);
  bool doY = (outY != nullptr) && (blockIdx.x == 0);
  int cc = tid & 127, hh = tid >> 7;
  float xA = 0, xB = 0, xP = 0, yA = 0, yB = 0, yP = 0;
  f32x4 acc[4][4] = {};
  uint4 a0 = {0,0,0,0}, a1 = {0,0,0,0}, b0 = {0,0,0,0}, b1 = {0,0,0,0};
  {
    int r0 = rb + 2 * sp, r1 = r0 + 1;
    if (r0 < re) {
      a0 = *(const uint4*)(Xm + (size_t)r0 * 256 + i0 + sc);
      b0 = *(const uint4*)(Ym + (size_t)r0 * 256 + j0 + sc);
    }
    if (r1 < re) {
      a1 = *(const uint4*)(Xm + (size_t)r1 * 256 + i0 + sc);
      b1 = *(const uint4*)(Ym + (size_t)r1 * 256 + j0 + sc);
    }
  }
  for (int rr = rb; rr < re; rr += 32) {
    __syncthreads();
    {
      const unsigned short* pa0 = (const unsigned short*)&a0;
      const unsigned short* pa1 = (const unsigned short*)&a1;
      const unsigned short* pb0 = (const unsigned short*)&b0;
      const unsigned short* pb1 = (const unsigned short*)&b1;
#pragma unroll
      for (int j = 0; j < 8; ++j) {
        *(unsigned int*)(ldsA + rp7(sc + j) * 36 + 2 * sp) =
            (unsigned int)pa0[j] | ((unsigned int)pa1[j] << 16);
        *(unsigned int*)(ldsB + rp7(sc + j) * 36 + 2 * sp) =
            (unsigned int)pb0[j] | ((unsigned int)pb1[j] << 16);
      }
    }
    if (tid < 128) {
      int grp = tid >> 5, kk = tid & 31, rw = rr + kk;
      const float* wp = (grp == 0) ? wxA : (grp == 1) ? wxB : (grp == 2) ? wyA : wyB;
      wls[grp][kk] = (wp && rw < re) ? wp[rw] : 0.f;
    }
    // issue next tile's loads; in flight during colsum + MFMA
    uint4 na0 = {0,0,0,0}, na1 = {0,0,0,0}, nb0 = {0,0,0,0}, nb1 = {0,0,0,0};
    int nr = rr + 32;
    if (nr < re) {
      int r0 = nr + 2 * sp, r1 = r0 + 1;
      if (r0 < re) {
        na0 = *(const uint4*)(Xm + (size_t)r0 * 256 + i0 + sc);
        nb0 = *(const uint4*)(Ym + (size_t)r0 * 256 + j0 + sc);
      }
      if (r1 < re) {
        na1 = *(const uint4*)(Xm + (size_t)r1 * 256 + i0 + sc);
        nb1 = *(const uint4*)(Ym + (size_t)r1 * 256 + j0 + sc);
      }
    }
    __syncthreads();
    if (doX) {
      const __half* p = ldsA + rp7(cc) * 36 + hh * 16;
#pragma unroll
      for (int k = 0; k < 16; ++k) {
        float v = __half2float(p[k]);
        xP += v; xA += v * wls[0][hh * 16 + k]; xB += v * wls[1][hh * 16 + k];
      }
    }
    if (doY) {
      const __half* p = ldsB + rp7(cc) * 36 + hh * 16;
#pragma unroll
      for (int k = 0; k < 16; ++k) {
        float v = __half2float(p[k]);
        yP += v; yA += v * wls[2][hh * 16 + k]; yB += v * wls[3][hh * 16 + k];
      }
    }
    f16x8 af[4];
#pragma unroll
    for (int fm = 0; fm < 4; ++fm) af[fm] = ldfrag(ldsA, wm * 64 + fm * 16 + lm, g);
#pragma unroll
    for (int fn = 0; fn < 4; ++fn) {
      f16x8 bf = ldfrag(ldsB, wn * 64 + fn * 16 + lm, g);
#pragma unroll
      for (int fm = 0; fm < 4; ++fm)
        acc[fm][fn] = __builtin_amdgcn_mfma_f32_16x16x32_f16(af[fm], bf, acc[fm][fn], 0, 0, 0);
    }
    a0 = na0; a1 = na1; b0 = nb0; b1 = nb1;
  }
  float* pout = partial + (size_t)z * 65536;
#pragma unroll
  for (int fm = 0; fm < 4; ++fm) {
#pragma unroll
    for (int reg = 0; reg < 4; ++reg) {
      int row = i0 + wm * 64 + fm * 16 + g * 4 + reg;
#pragma unroll
      for (int fn = 0; fn < 4; ++fn) {
        int col = j0 + wn * 64 + fn * 16 + lm;
        pout[(size_t)row * 256 + col] = acc[fm][fn][reg];
      }
    }
  }
  const float S6 = 4096.0f;   // 4^6
  float* fs = (float*)ldsA;
  if (doX) {
    __syncthreads();
    fs[hh * 128 + cc] = xA;
    __syncthreads();
    if (tid < 128) atomicAdd(&outX[i0 + tid], (fs[tid] + fs[128 + tid]) * S6);
    __syncthreads();
    fs[hh * 128 + cc] = xB;
    __syncthreads();
    if (tid < 128) atomicAdd(&outX[256 + i0 + tid], (fs[tid] + fs[128 + tid]) * S6);
    __syncthreads();
    fs[hh * 128 + cc] = xP;
    __syncthreads();
    if (tid < 128) atomicAdd(&outX[512 + i0 + tid], (fs[tid] + fs[128 + tid]) * S6);
  }
  if (doY) {
    __syncthreads();
    fs[hh * 128 + cc] = yA;
    __syncthreads();
    if (tid < 128) atomicAdd(&outY[j0 + tid], (fs[tid] + fs[128 + tid]) * S6);
    __syncthreads();
    fs[hh * 128 + cc] = yB;
    __syncthreads();
    if (tid < 128) atomicAdd(&outY[256 + j0 + tid], (fs[tid] + fs[128 + tid]) * S6);
    __syncthreads();
    fs[hh * 128 + cc] = yP;
    __syncthreads();
    if (tid < 128) atomicAdd(&outY[512 + j0 + tid], (fs[tid] + fs[128 + tid]) * S6);
  }
}

__global__ void k_gram_reduce(const float* __restrict__ partial, float* __restrict__ C) {
  int idx = blockIdx.x * 256 + threadIdx.x;
  float s = 0.f;
  for (int z = 0; z < GRAM_KS; ++z) s += partial[(size_t)z * 65536 + idx];
  C[idx] = s * 16777216.0f;   // *4^12
}

// ---------------- 8 scalar reductions over d/e vectors ----------------
// grid-stride, per-block LDS reduce, one atomic per block per counter
__global__ __launch_bounds__(256) void k_dots(const float* __restrict__ d1,
    const float* __restrict__ e1, const float* __restrict__ d2,
    const float* __restrict__ e2, float* scal, int n) {
  float s[8] = {};
  for (int i = blockIdx.x * 256 + threadIdx.x; i < n; i += gridDim.x * 256) {
    float a = d1[i], b = e1[i], c = d2[i], d = e2[i];
    s[0] += b * d; s[1] += b * c; s[2] += b; s[3] += a * d;
    s[4] += a * c; s[5] += a; s[6] += d; s[7] += c;
  }
  __shared__ float red[4][8];
  int lane = threadIdx.x & 63, w = threadIdx.x >> 6;
#pragma unroll
  for (int j = 0; j < 8; ++j)
    for (int off = 32; off; off >>= 1) s[j] += __shfl_down(s[j], off);
  if (lane == 0)
#pragma unroll
    for (int j = 0; j < 8; ++j) red[w][j] = s[j];
  __syncthreads();
  if (threadIdx.x < 8) {
    int j = threadIdx.x;
    atomicAdd(&scal[j], red[0][j] + red[1][j] + red[2][j] + red[3][j]);
  }
}

// ---------------- t_j = w_j^T C w_j ; mv_j = w_j . m_raw ----------------
__global__ __launch_bounds__(256) void k_quad(const float* __restrict__ C,
    const float* __restrict__ W1, const float* __restrict__ m_raw,
    float* __restrict__ t, float* __restrict__ mv) {
  __shared__ float w[256];
  __shared__ float r1[256], r2[256];
  int j = blockIdx.x, tid = threadIdx.x;
  w[tid] = W1[j * 256 + tid];
  __syncthreads();
  float v = 0.f;
  for (int k = 0; k < 256; ++k) v += w[k] * C[k * 256 + tid];
  r1[tid] = v * w[tid];
  r2[tid] = w[tid] * m_raw[tid];
  __syncthreads();
  for (int off = 128; off; off >>= 1) {
    if (tid < off) { r1[tid] += r1[tid + off]; r2[tid] += r2[tid + off]; }
    __syncthreads();
  }
  if (tid == 0) { t[j] = r1[0]; mv[j] = r2[0]; }
}

// ---------------- BN coefficients (coalesced W2T/W3T) ----------------
__global__ __launch_bounds__(256) void k_bncoef(const float* __restrict__ t,
    const float* __restrict__ mv, const float* __restrict__ b1,
    const float* __restrict__ gamma, const float* __restrict__ beta,
    const float* __restrict__ W2T, const float* __restrict__ W3T,
    const float* __restrict__ b2, float* Dv, float* xv, float* yv, int n) {
  __shared__ float c[256], u[256];
  int j = threadIdx.x;
  float invn = 1.f / (float)n;
  float mean = mv[j] * invn + b1[j];
  float E2 = t[j] * invn + 2.f * b1[j] * mv[j] * invn + b1[j] * b1[j];
  float var = E2 - mean * mean;
  float D = gamma[j] * rsqrtf(var + 1e-5f);
  Dv[j] = D;
  c[j] = D * (b1[j] - mean) + beta[j];
  __syncthreads();
  float uu = 0.f;
  for (int k = 0; k < 256; ++k) uu += W2T[k * 256 + j] * c[k];
  u[j] = uu;
  __syncthreads();
  float xx = 0.f, yy = 0.f;
  for (int k = 0; k < 256; ++k) {
    xx += W3T[k * 256 + j] * u[k];
    yy += W3T[k * 256 + j] * b2[k];
  }
  xv[j] = xx;
  yv[j] = yy;
}

// ---------------- small 256x256 matmul (B coalesced) ----------------
__global__ __launch_bounds__(256) void k_mm_small(float* __restrict__ Cm,
    const float* __restrict__ A, const float* __restrict__ B,
    const float* __restrict__ s, int transA) {
  __shared__ float a[256];
  int i = blockIdx.x, j = threadIdx.x;
  float av = transA ? A[j * 256 + i] : A[i * 256 + j];
  a[j] = s ? av * s[j] : av;
  __syncthreads();
  float acc = 0.f;
  for (int k = 0; k < 256; ++k) acc += a[k] * B[k * 256 + j];
  Cm[i * 256 + j] = acc;
}

// ---------------- 6 matvecs ----------------
__global__ __launch_bounds__(256) void k_mv6(const float* __restrict__ R1,
    const float* __restrict__ R2, const float* __restrict__ pX,
    const float* __restrict__ qY, float* __restrict__ vout) {
  __shared__ float w[256];
  int b = blockIdx.x, j = threadIdx.x;
  const float* M = (b < 3) ? R1 : R2;
  const float* wv = (b < 3) ? (pX + b * 256) : (qY + (b - 3) * 256);
  w[j] = wv[j];
  __syncthreads();
  float s = 0.f;
  for (int k = 0; k < 256; ++k) s += M[k * 256 + j] * w[k];
  vout[b * 256 + j] = s;
}

// ---------------- final ----------------
__global__ __launch_bounds__(256) void k_mm_final(float* __restrict__ out,
    const float* __restrict__ R1, const float* __restrict__ T1,
    const float* __restrict__ vout,
    const float* __restrict__ x1, const float* __restrict__ x2,
    const float* __restrict__ yv, const float* __restrict__ b3,
    const float* __restrict__ scal, float fN) {
  __shared__ float a[256];
  int i = blockIdx.x, j = threadIdx.x;
  a[j] = R1[j * 256 + i];
  __syncthreads();
  float acc = 0.f;
  for (int k = 0; k < 256; ++k) acc += a[k] * T1[k * 256 + j];
  float s1 = scal[0] * x2[j] + scal[1] * yv[j] + scal[2] * b3[j];
  float s2 = scal[3] * x2[j] + scal[4] * yv[j] + scal[5] * b3[j];
  float s3 = scal[6] * x2[j] + scal[7] * yv[j] + fN * b3[j];
  acc += vout[i] * x2[j] + vout[256 + i] * yv[j] + vout[512 + i] * b3[j];
  acc += x1[i] * (vout[768 + j] + s1) + yv[i] * (vout[1024 + j] + s2)
       + b3[i] * (vout[1280 + j] + s3);
  out[i * 256 + j] = acc;
}

extern "C" void kernel_launch(void* const* d_in, const int* in_sizes, int n_in,
                              void* d_out, int out_size, void* d_ws, size_t ws_size,
                              hipStream_t stream) {
  const float* feature = (const float*)d_in[0];
  const int* src1 = (const int*)d_in[1];
  const int* dst1 = (const int*)d_in[2];
  const int* src2 = (const int*)d_in[3];
  const int* dst2 = (const int*)d_in[4];
  const float* W1 = (const float*)d_in[5];
  const float* b1 = (const float*)d_in[6];
  const float* W2 = (const float*)d_in[7];
  const float* b2 = (const float*)d_in[8];
  const float* W3 = (const float*)d_in[9];
  const float* b3 = (const float*)d_in[10];
  const float* gamma = (const float*)d_in[11];
  const float* beta = (const float*)d_in[12];
  const int N = in_sizes[0] / FDIM;
  const int E = in_sizes[1];
  float* out = (float*)d_out;

  // ---- workspace layout (fp16 tables + dedicated fp32 partial) ----
  size_t NF = (size_t)N * FDIM;
  __half* FH = (__half*)d_ws;
  __half* Xh = FH + NF;
  __half* Yh = Xh + NF;
  __half* G2A = Yh + NF;
  float* partial = (float*)(G2A + NF);
  int* rowptr1 = (int*)(partial + (size_t)GRAM_KS * 65536);
  int* rowptr2 = rowptr1 + (N + 1);
  int* cursor = rowptr2 + (N + 1);
  int* esrc1 = cursor + N;
  int* esrc2 = esrc1 + E;
  float* vtmp1 = (float*)(esrc2 + E);
  float* vtmp2 = vtmp1 + N;
  float* d1 = vtmp2 + N; float* e1 = d1 + N; float* d2 = e1 + N; float* e2 = d2 + N;
  float* C = e2 + N;
  float* mcA = C + 65536;            // zeroed span start
  float* mcB = mcA + 256;
  float* pX = mcB + 256;
  float* qY = pX + 768;
  float* scal = qY + 768;
  float* tq = scal + 16; float* mv = tq + 256;
  float* Dv = mv + 256; float* x1 = Dv + 256; float* x2 = x1 + 256; float* yv = x2 + 256;
  float* Q = yv + 256; float* R1 = Q + 65536; float* R2 = R1 + 65536;
  float* Z = R2 + 65536; float* T1 = Z + 65536;
  float* W2T = T1 + 65536; float* W3T = W2T + 65536;
  float* vout = W3T + 65536;
  int* blksum = (int*)(vout + 1536);
  int* blkoff = blksum + 1024;
  int* gcur = blkoff + 1024;
  int2* pairs = (int2*)partial;      // scratch during CSR build (before grams)

  const int eb = (E + 255) / 256;
  const int aggb = (N + 3) / 4;
  const int avb2 = (2 * N * 16 + 255) / 256;
  const int nblk = (N + 1023) / 1024;
  int bshift = 0;
  while (((N - 1) >> bshift) >= NB) ++bshift;
  const int nbk = ((N - 1) >> bshift) + 1;
  const int pb = (E + 4095) / 4096;

  auto build = [&](const int* s_, const int* d_, int* rp, int* es) {
    hipMemsetAsync(cursor, 0, (size_t)N * sizeof(int), stream);
    k_hist<<<eb, 256, 0, stream>>>(d_, cursor, E);
    k_blksum<<<nblk, 256, 0, stream>>>(cursor, blksum, N);
    k_blkscan<<<1, 64, 0, stream>>>(blksum, blkoff, nblk);
    k_scan_blk<<<nblk, 256, 0, stream>>>(cursor, blkoff, rp, cursor, N);
    k_binit<<<1, 64, 0, stream>>>(rp, gcur, N, bshift);
    k_part<<<pb, 256, 0, stream>>>(s_, d_, gcur, pairs, E, bshift);
    k_scat2<<<nbk, 512, 0, stream>>>(pairs, rp, cursor, es, N, bshift);
  };

  k_tr2<<<dim3(4, 4, 2), 256, 0, stream>>>(W2, W3, W2T, W3T);
  k_f2h<<<(int)((NF / 4 + 255) / 256), 256, 0, stream>>>(feature, FH, (int)(NF / 4));
  build(src1, dst1, rowptr1, esrc1);
  build(src2, dst2, rowptr2, esrc2);
  hipMemsetAsync(mcA, 0, (256 * 2 + 768 * 2 + 16) * sizeof(float), stream);

  // ---- d/e vectors (fp32, exact) ----
  k_aggv2<<<avb2, 256, 0, stream>>>(nullptr, nullptr, rowptr1, esrc1, rowptr2, esrc2,
                                    d1, d2, N, 1);
  k_aggv2<<<avb2, 256, 0, stream>>>(d1, d2, rowptr1, esrc1, rowptr2, esrc2,
                                    vtmp1, vtmp2, N, 0);
  k_aggv2<<<avb2, 256, 0, stream>>>(vtmp1, vtmp2, rowptr1, esrc1, rowptr2, esrc2,
                                    e1, e2, N, 0);
  k_dots<<<64, 256, 0, stream>>>(d1, e1, d2, e2, scal, N);

  auto do_branch = [&](const int* rp, const int* es, __half* G2dst,
                       float* mc, float* xvec, float* Rdst) {
    k_aggh<<<aggb, 256, 0, stream>>>(FH, rp, es, Xh, N);
    k_aggh<<<aggb, 256, 0, stream>>>(Xh, rp, es, Yh, N);              // Yh = G0/16
    k_gram_sym<<<dim3(3, 1, GRAM_KS), 256, 0, stream>>>(Yh, partial, N, mc);
    k_gram_reduce_sym<<<256, 256, 0, stream>>>(partial, C);           // C true scale
    k_quad<<<256, 256, 0, stream>>>(C, W1, mc, tq, mv);
    k_bncoef<<<1, 256, 0, stream>>>(tq, mv, b1, gamma, beta, W2T, W3T, b2, Dv, xvec, yv, N);
    k_mm_small<<<256, 256, 0, stream>>>(Q, W1, W2T, Dv, 1);
    k_mm_small<<<256, 256, 0, stream>>>(Rdst, Q, W3T, nullptr, 0);
    k_aggh<<<aggb, 256, 0, stream>>>(Yh, rp, es, Xh, N);
    k_aggh<<<aggb, 256, 0, stream>>>(Xh, rp, es, Yh, N);              // A^4 F /256
    k_aggh<<<aggb, 256, 0, stream>>>(Yh, rp, es, Xh, N);
    k_aggh<<<aggb, 256, 0, stream>>>(Xh, rp, es, G2dst, N);           // G2/4096
  };

  do_branch(rowptr1, esrc1, G2A, mcA, x1, R1);
  do_branch(rowptr2, esrc2, Yh, mcB, x2, R2);   // branch-2 G2 lands in Yh

  // ---- final: Z = G2_1^T G2_2 (rescaled) + fused weighted colsums ----
  k_gram<<<dim3(2, 2, GRAM_KS), 256, 0, stream>>>(G2A, Yh, partial, N,
      e2, d2, pX, e1, d1, qY);
  k_gram_reduce<<<256, 256, 0, stream>>>(partial, Z);

  k_mm_small<<<256, 256, 0, stream>>>(T1, Z, R2, nullptr, 0);
  k_mv6<<<6, 256, 0, stream>>>(R1, R2, pX, qY, vout);
  k_mm_final<<<256, 256, 0, stream>>>(out, R1, T1, vout, x1, x2, yv, b3, scal, (float)N);
}